// Round 1
// baseline (955.799 us; speedup 1.0000x reference)
//
#include <hip/hip_runtime.h>
#include <math.h>

constexpr int Bz = 4, Cc = 64, Hh = 128, Ww = 128, Kk = 9;
constexpr int HW = Hh * Ww;              // 16384
constexpr float EPSf = 1e-5f;
constexpr int TPX = 16;                  // pixels per deform block
constexpr int CK = Cc * Kk;              // 576

// ---- weight transpose: wT[ck][o] = w[o][ck], both blocks in one launch ----
__global__ void wtrans_kernel(const float* __restrict__ w1, const float* __restrict__ w2,
                              float* __restrict__ wT1, float* __restrict__ wT2) {
    int i = blockIdx.x * 256 + threadIdx.x;
    if (i >= 2 * CK * 64) return;
    const float* src = (i < CK * 64) ? w1 : w2;
    float* dst = (i < CK * 64) ? wT1 : wT2;
    int j = i % (CK * 64);
    int o = j % 64, ck = j / 64;
    dst[ck * 64 + o] = src[o * CK + ck];
}

// ---- offset conv: direct 3x3, Cin=64, Cout=18, SAME pad ----
__global__ __launch_bounds__(256)
void offconv_kernel(const float* __restrict__ x, const float* __restrict__ ow,
                    const float* __restrict__ ob, float* __restrict__ off) {
    int tid = blockIdx.x * 256 + threadIdx.x;          // B*18*H*W = 1,179,648
    int w = tid % Ww;
    int h = (tid / Ww) % Hh;
    int oc = (tid / HW) % 18;
    int b = tid / (18 * HW);
    float acc = ob[oc];
    const float* xb = x + (size_t)b * Cc * HW;
    const float* wb = ow + (size_t)oc * CK;
    for (int c = 0; c < Cc; c++) {
        const float* xc = xb + (size_t)c * HW;
        const float* wc = wb + c * 9;
        #pragma unroll
        for (int ky = 0; ky < 3; ky++) {
            int yy = h + ky - 1;
            if ((unsigned)yy >= (unsigned)Hh) continue;
            #pragma unroll
            for (int kx = 0; kx < 3; kx++) {
                int xx = w + kx - 1;
                if ((unsigned)xx >= (unsigned)Ww) continue;
                acc += xc[yy * Ww + xx] * wc[ky * 3 + kx];
            }
        }
    }
    off[tid] = acc;
}

// ---- deformable conv: one block = 16 consecutive pixels of one (b,h) row ----
__global__ __launch_bounds__(256)
void deform_kernel(const float* __restrict__ x, const float* __restrict__ wT,
                   const float* __restrict__ bias, const float* __restrict__ off,
                   float* __restrict__ y) {
    __shared__ float s_samp[TPX][CK + 1];   // +1 pad: stagger staging-write banks
    __shared__ float s_wy[TPX][Kk], s_wx[TPX][Kk];
    __shared__ int   s_y0[TPX][Kk], s_x0[TPX][Kk];

    int blk = blockIdx.x;                   // B * Hh * (Ww/TPX) = 4096
    int wt = blk % (Ww / TPX);
    int h  = (blk / (Ww / TPX)) % Hh;
    int b  = blk / ((Ww / TPX) * Hh);
    int w0 = wt * TPX;
    int t = threadIdx.x;

    // phase 0: bilinear coords per (pixel, tap)
    if (t < TPX * Kk) {
        int p = t % TPX, k = t / TPX;
        int ky = k / 3, kx = k % 3;
        size_t obase = ((size_t)(b * 18 + 2 * k)) * HW + h * Ww + w0 + p;
        float ody = off[obase];
        float odx = off[obase + HW];
        float cy = (float)h + (float)(ky - 1) + ody;
        float cx = (float)(w0 + p) + (float)(kx - 1) + odx;
        float fy = floorf(cy), fx = floorf(cx);
        s_wy[p][k] = cy - fy;  s_wx[p][k] = cx - fx;
        s_y0[p][k] = (int)fy;  s_x0[p][k] = (int)fx;
    }
    __syncthreads();

    // phase 1: gather + bilinear into LDS sample matrix [pixel][c*9+k]
    {
        int p = t % TPX;
        int cbase = t / TPX;                 // 0..15
        const float* xb = x + (size_t)b * Cc * HW;
        for (int pass = 0; pass < 4; pass++) {
            int c = pass * 16 + cbase;
            const float* xc = xb + (size_t)c * HW;
            #pragma unroll
            for (int k = 0; k < Kk; k++) {
                int y0 = s_y0[p][k], x0 = s_x0[p][k];
                float wy = s_wy[p][k], wx = s_wx[p][k];
                int y1 = y0 + 1, x1 = x0 + 1;
                bool vy0 = (unsigned)y0 < (unsigned)Hh, vy1 = (unsigned)y1 < (unsigned)Hh;
                bool vx0 = (unsigned)x0 < (unsigned)Ww, vx1 = (unsigned)x1 < (unsigned)Ww;
                float v00 = (vy0 && vx0) ? xc[y0 * Ww + x0] : 0.f;
                float v01 = (vy0 && vx1) ? xc[y0 * Ww + x1] : 0.f;
                float v10 = (vy1 && vx0) ? xc[y1 * Ww + x0] : 0.f;
                float v11 = (vy1 && vx1) ? xc[y1 * Ww + x1] : 0.f;
                s_samp[p][c * 9 + k] =
                    (1.f - wy) * ((1.f - wx) * v00 + wx * v01) +
                    wy * ((1.f - wx) * v10 + wx * v11);
            }
        }
    }
    __syncthreads();

    // phase 2: 4 waves, lane = out-channel, 4 pixels per wave
    int wave = t >> 6, lane = t & 63;
    int pb = wave * 4;
    float acc0 = 0.f, acc1 = 0.f, acc2 = 0.f, acc3 = 0.f;
    for (int ck = 0; ck < CK; ck++) {
        float wv = wT[ck * 64 + lane];        // coalesced 256B per wave
        acc0 += s_samp[pb + 0][ck] * wv;      // LDS broadcast reads
        acc1 += s_samp[pb + 1][ck] * wv;
        acc2 += s_samp[pb + 2][ck] * wv;
        acc3 += s_samp[pb + 3][ck] * wv;
    }
    float bb = bias[lane];
    size_t ob = ((size_t)(b * Cc + lane)) * HW + h * Ww + w0 + pb;
    y[ob + 0] = acc0 + bb;
    y[ob + 1] = acc1 + bb;
    y[ob + 2] = acc2 + bb;
    y[ob + 3] = acc3 + bb;
}

// ---- GroupNorm(1): stage A partial sums (64 blocks/sample, no atomics) ----
__global__ __launch_bounds__(256)
void gn_partial_kernel(const float* __restrict__ y, float* __restrict__ part) {
    int b = blockIdx.x >> 6;
    int blk = blockIdx.x & 63;
    const float* yb = y + (size_t)b * Cc * HW;
    const int n = Cc * HW;                    // 1,048,576
    float s = 0.f, s2 = 0.f;
    for (int i = blk * 256 + threadIdx.x; i < n; i += 64 * 256) {
        float v = yb[i];
        s += v; s2 += v * v;
    }
    for (int o = 32; o > 0; o >>= 1) {
        s  += __shfl_down(s, o);
        s2 += __shfl_down(s2, o);
    }
    __shared__ float ls[4][2];
    int wave = threadIdx.x >> 6, lane = threadIdx.x & 63;
    if (lane == 0) { ls[wave][0] = s; ls[wave][1] = s2; }
    __syncthreads();
    if (threadIdx.x == 0) {
        float a = 0.f, c = 0.f;
        for (int i = 0; i < 4; i++) { a += ls[i][0]; c += ls[i][1]; }
        part[blockIdx.x * 2]     = a;
        part[blockIdx.x * 2 + 1] = c;
    }
}

// ---- GroupNorm(1): stage B final mean / rsqrt(var+eps), one block/sample ----
__global__ void gn_final_kernel(const float* __restrict__ part, float* __restrict__ stats) {
    int b = blockIdx.x;
    int l = threadIdx.x;                      // 64 threads
    float s  = part[(b * 64 + l) * 2];
    float s2 = part[(b * 64 + l) * 2 + 1];
    for (int o = 32; o > 0; o >>= 1) {
        s  += __shfl_down(s, o);
        s2 += __shfl_down(s2, o);
    }
    if (l == 0) {
        const float n = (float)(Cc * HW);
        float m = s / n;
        float var = s2 / n - m * m;
        stats[b * 2]     = m;
        stats[b * 2 + 1] = rsqrtf(var + EPSf);
    }
}

// ---- normalize + ReLU + residual ----
__global__ __launch_bounds__(256)
void gn_finalize_kernel(const float* __restrict__ y, const float* __restrict__ res,
                        const float* __restrict__ g, const float* __restrict__ be,
                        const float* __restrict__ stats, float* __restrict__ out) {
    int idx = blockIdx.x * 256 + threadIdx.x;  // B*C*H*W = 4,194,304
    int c = (idx >> 14) & 63;                  // HW = 2^14
    int b = idx >> 20;                         // C*HW = 2^20
    float m = stats[b * 2], rs = stats[b * 2 + 1];
    float v = (y[idx] - m) * rs * g[c] + be[c];
    out[idx] = fmaxf(v, 0.f) + res[idx];
}

extern "C" void kernel_launch(void* const* d_in, const int* in_sizes, int n_in,
                              void* d_out, int out_size, void* d_ws, size_t ws_size,
                              hipStream_t stream) {
    const float* x   = (const float*)d_in[0];
    const float* w1  = (const float*)d_in[1];
    const float* b1  = (const float*)d_in[2];
    const float* ow1 = (const float*)d_in[3];
    const float* ob1 = (const float*)d_in[4];
    const float* g1  = (const float*)d_in[5];
    const float* be1 = (const float*)d_in[6];
    const float* w2  = (const float*)d_in[7];
    const float* b2  = (const float*)d_in[8];
    const float* ow2 = (const float*)d_in[9];
    const float* ob2 = (const float*)d_in[10];
    const float* g2  = (const float*)d_in[11];
    const float* be2 = (const float*)d_in[12];
    float* out = (float*)d_out;

    float* ws    = (float*)d_ws;
    float* off   = ws;                                  // B*18*HW = 1,179,648
    float* ybuf  = off + (size_t)Bz * 18 * HW;          // B*C*HW  = 4,194,304
    float* h1    = ybuf + (size_t)Bz * Cc * HW;         // B*C*HW
    float* wT1   = h1 + (size_t)Bz * Cc * HW;           // 576*64
    float* wT2   = wT1 + CK * 64;                       // 576*64
    float* part  = wT2 + CK * 64;                       // 256*2
    float* stats = part + 512;                          // 4*2

    wtrans_kernel<<<(2 * CK * 64 + 255) / 256, 256, 0, stream>>>(w1, w2, wT1, wT2);

    // block 1: deform_conv -> GN -> relu -> +x
    offconv_kernel<<<Bz * 18 * HW / 256, 256, 0, stream>>>(x, ow1, ob1, off);
    deform_kernel<<<Bz * Hh * (Ww / TPX), 256, 0, stream>>>(x, wT1, b1, off, ybuf);
    gn_partial_kernel<<<256, 256, 0, stream>>>(ybuf, part);
    gn_final_kernel<<<4, 64, 0, stream>>>(part, stats);
    gn_finalize_kernel<<<Bz * Cc * HW / 256, 256, 0, stream>>>(ybuf, x, g1, be1, stats, h1);

    // block 2: deform_conv -> GN -> relu -> +h1
    offconv_kernel<<<Bz * 18 * HW / 256, 256, 0, stream>>>(h1, ow2, ob2, off);
    deform_kernel<<<Bz * Hh * (Ww / TPX), 256, 0, stream>>>(h1, wT2, b2, off, ybuf);
    gn_partial_kernel<<<256, 256, 0, stream>>>(ybuf, part);
    gn_final_kernel<<<4, 64, 0, stream>>>(part, stats);
    gn_finalize_kernel<<<Bz * Cc * HW / 256, 256, 0, stream>>>(ybuf, h1, g2, be2, stats, out);
}

// Round 2
// 635.371 us; speedup vs baseline: 1.5043x; 1.5043x over previous
//
#include <hip/hip_runtime.h>
#include <math.h>

constexpr int Bz = 4, Cc = 64, Hh = 128, Ww = 128, Kk = 9;
constexpr int HW = Hh * Ww;              // 16384
constexpr float EPSf = 1e-5f;
constexpr int TPX = 16;                  // pixels per deform block
constexpr int CK = Cc * Kk;              // 576

// ---- weight transpose: wT[ck][o] = w[o][ck], both blocks in one launch ----
__global__ void wtrans_kernel(const float* __restrict__ w1, const float* __restrict__ w2,
                              float* __restrict__ wT1, float* __restrict__ wT2) {
    int i = blockIdx.x * 256 + threadIdx.x;
    if (i >= 2 * CK * 64) return;
    const float* src = (i < CK * 64) ? w1 : w2;
    float* dst = (i < CK * 64) ? wT1 : wT2;
    int j = i % (CK * 64);
    int o = j % 64, ck = j / 64;
    dst[ck * 64 + o] = src[o * CK + ck];
}

// ---- offset conv: LDS-tiled 3x3, Cin=64, Cout=18, SAME pad ----
// block = 64 consecutive pixels of one (b,h) row; lane = pixel, wave = oc-group
__global__ __launch_bounds__(256)
void offconv_kernel(const float* __restrict__ x, const float* __restrict__ ow,
                    const float* __restrict__ ob, float* __restrict__ off) {
    __shared__ float s_x[Cc][3][66];     // 50.7 KB: x[ch][row-1..row+1][w0-1..w0+64]

    int blk = blockIdx.x;                // B * Hh * (Ww/64) = 1024
    int wt = blk & 1;
    int h  = (blk >> 1) & (Hh - 1);
    int b  = blk >> 8;
    int w0 = wt * 64;
    int t = threadIdx.x;

    // stage x tile (coalesced; zero-fill halo)
    for (int idx = t; idx < Cc * 3 * 66; idx += 256) {
        int row = idx / 66;
        int col = idx - row * 66;
        int c = row / 3, r = row - c * 3;
        int gy = h - 1 + r;
        int gx = w0 - 1 + col;
        float v = 0.f;
        if ((unsigned)gy < (unsigned)Hh && (unsigned)gx < (unsigned)Ww)
            v = x[(((size_t)b * Cc + c) * Hh + gy) * Ww + gx];
        s_x[c][r][col] = v;
    }
    __syncthreads();

    int wave = __builtin_amdgcn_readfirstlane(t >> 6);  // force wave-uniform -> s_load weights
    int p = t & 63;

    float acc[5];
    #pragma unroll
    for (int i = 0; i < 5; i++) {
        int o = wave + 4 * i;
        acc[i] = (o < 18) ? ob[o] : 0.f;
    }

    for (int c = 0; c < Cc; c++) {
        float wreg[5][9];
        #pragma unroll
        for (int i = 0; i < 5; i++) {
            int o = wave + 4 * i;
            const float* wp = ow + (size_t)(o < 18 ? o : 17) * CK + c * 9;
            #pragma unroll
            for (int k = 0; k < 9; k++) wreg[i][k] = wp[k];
        }
        #pragma unroll
        for (int ky = 0; ky < 3; ky++) {
            const float* rowp = &s_x[c][ky][p];
            float x0 = rowp[0], x1 = rowp[1], x2 = rowp[2];
            #pragma unroll
            for (int i = 0; i < 5; i++)
                acc[i] += x0 * wreg[i][ky * 3 + 0]
                        + x1 * wreg[i][ky * 3 + 1]
                        + x2 * wreg[i][ky * 3 + 2];
        }
    }

    size_t base = (size_t)b * 18 * HW + h * Ww + w0 + p;
    #pragma unroll
    for (int i = 0; i < 5; i++) {
        int o = wave + 4 * i;
        if (o < 18) off[base + (size_t)o * HW] = acc[i];
    }
}

// ---- deformable conv: one block = 16 consecutive pixels of one (b,h) row ----
__global__ __launch_bounds__(256)
void deform_kernel(const float* __restrict__ x, const float* __restrict__ wT,
                   const float* __restrict__ bias, const float* __restrict__ off,
                   float* __restrict__ y) {
    __shared__ float s_samp[TPX][CK + 1];   // +1 pad: stagger staging-write banks
    __shared__ float s_wy[TPX][Kk], s_wx[TPX][Kk];
    __shared__ int   s_y0[TPX][Kk], s_x0[TPX][Kk];

    int blk = blockIdx.x;                   // B * Hh * (Ww/TPX) = 4096
    int wt = blk % (Ww / TPX);
    int h  = (blk / (Ww / TPX)) % Hh;
    int b  = blk / ((Ww / TPX) * Hh);
    int w0 = wt * TPX;
    int t = threadIdx.x;

    // phase 0: bilinear coords per (pixel, tap)
    if (t < TPX * Kk) {
        int p = t % TPX, k = t / TPX;
        int ky = k / 3, kx = k % 3;
        size_t obase = ((size_t)(b * 18 + 2 * k)) * HW + h * Ww + w0 + p;
        float ody = off[obase];
        float odx = off[obase + HW];
        float cy = (float)h + (float)(ky - 1) + ody;
        float cx = (float)(w0 + p) + (float)(kx - 1) + odx;
        float fy = floorf(cy), fx = floorf(cx);
        s_wy[p][k] = cy - fy;  s_wx[p][k] = cx - fx;
        s_y0[p][k] = (int)fy;  s_x0[p][k] = (int)fx;
    }
    __syncthreads();

    // phase 1: gather + bilinear into LDS sample matrix [pixel][c*9+k]
    {
        int p = t % TPX;
        int cbase = t / TPX;                 // 0..15
        const float* xb = x + (size_t)b * Cc * HW;
        for (int pass = 0; pass < 4; pass++) {
            int c = pass * 16 + cbase;
            const float* xc = xb + (size_t)c * HW;
            #pragma unroll
            for (int k = 0; k < Kk; k++) {
                int y0 = s_y0[p][k], x0 = s_x0[p][k];
                float wy = s_wy[p][k], wx = s_wx[p][k];
                int y1 = y0 + 1, x1 = x0 + 1;
                bool vy0 = (unsigned)y0 < (unsigned)Hh, vy1 = (unsigned)y1 < (unsigned)Hh;
                bool vx0 = (unsigned)x0 < (unsigned)Ww, vx1 = (unsigned)x1 < (unsigned)Ww;
                float v00 = (vy0 && vx0) ? xc[y0 * Ww + x0] : 0.f;
                float v01 = (vy0 && vx1) ? xc[y0 * Ww + x1] : 0.f;
                float v10 = (vy1 && vx0) ? xc[y1 * Ww + x0] : 0.f;
                float v11 = (vy1 && vx1) ? xc[y1 * Ww + x1] : 0.f;
                s_samp[p][c * 9 + k] =
                    (1.f - wy) * ((1.f - wx) * v00 + wx * v01) +
                    wy * ((1.f - wx) * v10 + wx * v11);
            }
        }
    }
    __syncthreads();

    // phase 2: 4 waves, lane = out-channel, 4 pixels per wave
    int wave = t >> 6, lane = t & 63;
    int pb = wave * 4;
    float acc0 = 0.f, acc1 = 0.f, acc2 = 0.f, acc3 = 0.f;
    for (int ck = 0; ck < CK; ck++) {
        float wv = wT[ck * 64 + lane];        // coalesced 256B per wave
        acc0 += s_samp[pb + 0][ck] * wv;      // LDS broadcast reads
        acc1 += s_samp[pb + 1][ck] * wv;
        acc2 += s_samp[pb + 2][ck] * wv;
        acc3 += s_samp[pb + 3][ck] * wv;
    }
    float bb = bias[lane];
    size_t ob = ((size_t)(b * Cc + lane)) * HW + h * Ww + w0 + pb;
    y[ob + 0] = acc0 + bb;
    y[ob + 1] = acc1 + bb;
    y[ob + 2] = acc2 + bb;
    y[ob + 3] = acc3 + bb;
}

// ---- GroupNorm(1): stage A partial sums (64 blocks/sample, no atomics) ----
__global__ __launch_bounds__(256)
void gn_partial_kernel(const float* __restrict__ y, float* __restrict__ part) {
    int b = blockIdx.x >> 6;
    int blk = blockIdx.x & 63;
    const float* yb = y + (size_t)b * Cc * HW;
    const int n = Cc * HW;                    // 1,048,576
    float s = 0.f, s2 = 0.f;
    for (int i = blk * 256 + threadIdx.x; i < n; i += 64 * 256) {
        float v = yb[i];
        s += v; s2 += v * v;
    }
    for (int o = 32; o > 0; o >>= 1) {
        s  += __shfl_down(s, o);
        s2 += __shfl_down(s2, o);
    }
    __shared__ float ls[4][2];
    int wave = threadIdx.x >> 6, lane = threadIdx.x & 63;
    if (lane == 0) { ls[wave][0] = s; ls[wave][1] = s2; }
    __syncthreads();
    if (threadIdx.x == 0) {
        float a = 0.f, c = 0.f;
        for (int i = 0; i < 4; i++) { a += ls[i][0]; c += ls[i][1]; }
        part[blockIdx.x * 2]     = a;
        part[blockIdx.x * 2 + 1] = c;
    }
}

// ---- GroupNorm(1): stage B final mean / rsqrt(var+eps), one block/sample ----
__global__ void gn_final_kernel(const float* __restrict__ part, float* __restrict__ stats) {
    int b = blockIdx.x;
    int l = threadIdx.x;                      // 64 threads
    float s  = part[(b * 64 + l) * 2];
    float s2 = part[(b * 64 + l) * 2 + 1];
    for (int o = 32; o > 0; o >>= 1) {
        s  += __shfl_down(s, o);
        s2 += __shfl_down(s2, o);
    }
    if (l == 0) {
        const float n = (float)(Cc * HW);
        float m = s / n;
        float var = s2 / n - m * m;
        stats[b * 2]     = m;
        stats[b * 2 + 1] = rsqrtf(var + EPSf);
    }
}

// ---- normalize + ReLU + residual ----
__global__ __launch_bounds__(256)
void gn_finalize_kernel(const float* __restrict__ y, const float* __restrict__ res,
                        const float* __restrict__ g, const float* __restrict__ be,
                        const float* __restrict__ stats, float* __restrict__ out) {
    int idx = blockIdx.x * 256 + threadIdx.x;  // B*C*H*W = 4,194,304
    int c = (idx >> 14) & 63;                  // HW = 2^14
    int b = idx >> 20;                         // C*HW = 2^20
    float m = stats[b * 2], rs = stats[b * 2 + 1];
    float v = (y[idx] - m) * rs * g[c] + be[c];
    out[idx] = fmaxf(v, 0.f) + res[idx];
}

extern "C" void kernel_launch(void* const* d_in, const int* in_sizes, int n_in,
                              void* d_out, int out_size, void* d_ws, size_t ws_size,
                              hipStream_t stream) {
    const float* x   = (const float*)d_in[0];
    const float* w1  = (const float*)d_in[1];
    const float* b1  = (const float*)d_in[2];
    const float* ow1 = (const float*)d_in[3];
    const float* ob1 = (const float*)d_in[4];
    const float* g1  = (const float*)d_in[5];
    const float* be1 = (const float*)d_in[6];
    const float* w2  = (const float*)d_in[7];
    const float* b2  = (const float*)d_in[8];
    const float* ow2 = (const float*)d_in[9];
    const float* ob2 = (const float*)d_in[10];
    const float* g2  = (const float*)d_in[11];
    const float* be2 = (const float*)d_in[12];
    float* out = (float*)d_out;

    float* ws    = (float*)d_ws;
    float* off   = ws;                                  // B*18*HW = 1,179,648
    float* ybuf  = off + (size_t)Bz * 18 * HW;          // B*C*HW  = 4,194,304
    float* h1    = ybuf + (size_t)Bz * Cc * HW;         // B*C*HW
    float* wT1   = h1 + (size_t)Bz * Cc * HW;           // 576*64
    float* wT2   = wT1 + CK * 64;                       // 576*64
    float* part  = wT2 + CK * 64;                       // 256*2
    float* stats = part + 512;                          // 4*2

    wtrans_kernel<<<(2 * CK * 64 + 255) / 256, 256, 0, stream>>>(w1, w2, wT1, wT2);

    // block 1: deform_conv -> GN -> relu -> +x
    offconv_kernel<<<Bz * Hh * (Ww / 64), 256, 0, stream>>>(x, ow1, ob1, off);
    deform_kernel<<<Bz * Hh * (Ww / TPX), 256, 0, stream>>>(x, wT1, b1, off, ybuf);
    gn_partial_kernel<<<256, 256, 0, stream>>>(ybuf, part);
    gn_final_kernel<<<4, 64, 0, stream>>>(part, stats);
    gn_finalize_kernel<<<Bz * Cc * HW / 256, 256, 0, stream>>>(ybuf, x, g1, be1, stats, h1);

    // block 2: deform_conv -> GN -> relu -> +h1
    offconv_kernel<<<Bz * Hh * (Ww / 64), 256, 0, stream>>>(h1, ow2, ob2, off);
    deform_kernel<<<Bz * Hh * (Ww / TPX), 256, 0, stream>>>(h1, wT2, b2, off, ybuf);
    gn_partial_kernel<<<256, 256, 0, stream>>>(ybuf, part);
    gn_final_kernel<<<4, 64, 0, stream>>>(part, stats);
    gn_finalize_kernel<<<Bz * Cc * HW / 256, 256, 0, stream>>>(ybuf, h1, g2, be2, stats, out);
}

// Round 3
// 316.297 us; speedup vs baseline: 3.0218x; 2.0088x over previous
//
#include <hip/hip_runtime.h>
#include <math.h>

constexpr int Bz = 4, Cc = 64, Hh = 128, Ww = 128, Kk = 9;
constexpr int HW = Hh * Ww;              // 16384
constexpr float EPSf = 1e-5f;
constexpr int CK = Cc * Kk;              // 576

typedef __attribute__((ext_vector_type(8))) short short8;
typedef __attribute__((ext_vector_type(4))) float f32x4;

__device__ __forceinline__ ushort f32_to_bf16(float f) {
    uint u = __float_as_uint(f);
    return (ushort)((u + 0x7fffu + ((u >> 16) & 1u)) >> 16);   // RNE
}

// ---- weight fragment prep: wA[(wo*18+kk)*64+l][j] = w[oc][c][tap] (bf16) ----
// oc = wo*16 + (l&15); kidx = kk*32 + (l>>4)*8 + j; tap = kidx>>6; c = kidx&63
__global__ void wfrag_kernel(const float* __restrict__ w1, const float* __restrict__ w2,
                             ushort* __restrict__ wA1, ushort* __restrict__ wA2) {
    int tid = blockIdx.x * 256 + threadIdx.x;     // 2 * 36864
    if (tid >= 2 * 36864) return;
    const float* w = (tid < 36864) ? w1 : w2;
    ushort* dst = (tid < 36864) ? wA1 : wA2;
    int e = tid % 36864;
    int j = e & 7, l = (e >> 3) & 63, kk = (e >> 9) % 18, wo = e / 9216;
    int oc = wo * 16 + (l & 15);
    int kidx = kk * 32 + ((l >> 4) * 8) + j;
    int tap = kidx >> 6, c = kidx & 63;
    dst[e] = f32_to_bf16(w[oc * CK + c * 9 + tap]);
}

// ---- NCHW fp32 -> NHWC bf16 (tiled transpose) ----
__global__ __launch_bounds__(256)
void nhwc_kernel(const float* __restrict__ src, ushort* __restrict__ dst) {
    __shared__ float s_t[64][65];
    int blk = blockIdx.x;                 // Bz * (HW/64) = 1024
    int p0 = (blk & 255) * 64;
    int b = blk >> 8;
    int t = threadIdx.x;
    int tp = t & 63;
    #pragma unroll
    for (int i = 0; i < 16; i++) {
        int c = i * 4 + (t >> 6);
        s_t[c][tp] = src[((size_t)(b * 64 + c)) * HW + p0 + tp];
    }
    __syncthreads();
    #pragma unroll
    for (int i = 0; i < 16; i++) {
        int pl = i * 4 + (t >> 6);
        dst[((size_t)b * HW + p0 + pl) * 64 + tp] = f32_to_bf16(s_t[tp][pl]);
    }
}

// ---- offset conv: LDS-tiled 3x3, Cin=64, Cout=18, SAME pad (unchanged) ----
__global__ __launch_bounds__(256)
void offconv_kernel(const float* __restrict__ x, const float* __restrict__ ow,
                    const float* __restrict__ ob, float* __restrict__ off) {
    __shared__ float s_x[Cc][3][66];

    int blk = blockIdx.x;                // B * Hh * (Ww/64) = 1024
    int wt = blk & 1;
    int h  = (blk >> 1) & (Hh - 1);
    int b  = blk >> 8;
    int w0 = wt * 64;
    int t = threadIdx.x;

    for (int idx = t; idx < Cc * 3 * 66; idx += 256) {
        int row = idx / 66;
        int col = idx - row * 66;
        int c = row / 3, r = row - c * 3;
        int gy = h - 1 + r;
        int gx = w0 - 1 + col;
        float v = 0.f;
        if ((unsigned)gy < (unsigned)Hh && (unsigned)gx < (unsigned)Ww)
            v = x[(((size_t)b * Cc + c) * Hh + gy) * Ww + gx];
        s_x[c][r][col] = v;
    }
    __syncthreads();

    int wave = __builtin_amdgcn_readfirstlane(t >> 6);
    int p = t & 63;

    float acc[5];
    #pragma unroll
    for (int i = 0; i < 5; i++) {
        int o = wave + 4 * i;
        acc[i] = (o < 18) ? ob[o] : 0.f;
    }

    for (int c = 0; c < Cc; c++) {
        float wreg[5][9];
        #pragma unroll
        for (int i = 0; i < 5; i++) {
            int o = wave + 4 * i;
            const float* wp = ow + (size_t)(o < 18 ? o : 17) * CK + c * 9;
            #pragma unroll
            for (int k = 0; k < 9; k++) wreg[i][k] = wp[k];
        }
        #pragma unroll
        for (int ky = 0; ky < 3; ky++) {
            const float* rowp = &s_x[c][ky][p];
            float x0 = rowp[0], x1 = rowp[1], x2 = rowp[2];
            #pragma unroll
            for (int i = 0; i < 5; i++)
                acc[i] += x0 * wreg[i][ky * 3 + 0]
                        + x1 * wreg[i][ky * 3 + 1]
                        + x2 * wreg[i][ky * 3 + 2];
        }
    }

    size_t base = (size_t)b * 18 * HW + h * Ww + w0 + p;
    #pragma unroll
    for (int i = 0; i < 5; i++) {
        int o = wave + 4 * i;
        if (o < 18) off[base + (size_t)o * HW] = acc[i];
    }
}

// ---- deformable conv via MFMA: block = 32 px of one (b,h) row, 512 thr ----
__global__ __launch_bounds__(512, 4)
void deform_mfma_kernel(const ushort* __restrict__ xnh, const ushort* __restrict__ wA,
                        const float* __restrict__ bias, const float* __restrict__ off,
                        float* __restrict__ y) {
    __shared__ __align__(16) ushort s_a[32 * 584];    // A[px][tap*64+c] bf16, +8 pad
    __shared__ __align__(16) uint   s_aw[32 * 9 * 8]; // per (px,tap): 4x{addr,wgt}

    int blk = blockIdx.x;            // Bz*Hh*(Ww/32) = 2048
    int wt = blk & 3;
    int h  = (blk >> 2) & 127;
    int b  = blk >> 9;
    int w0 = wt * 32;
    int t = threadIdx.x;

    // phase 0: bilinear coords -> clamped corner addrs + validity-folded weights
    if (t < 288) {
        int px = t / 9, k = t - px * 9;
        int ky = k / 3 - 1, kx = k - (k / 3) * 3 - 1;
        size_t obase = ((size_t)(b * 18 + 2 * k)) * HW + h * Ww + w0 + px;
        float ody = off[obase];
        float odx = off[obase + HW];
        float cy = (float)(h + ky) + ody;
        float cx = (float)(w0 + px + kx) + odx;
        float fy = floorf(cy), fx = floorf(cx);
        float wy = cy - fy, wx = cx - fx;
        int y0 = (int)fy, x0 = (int)fx;
        int yy[2] = {y0, y0 + 1}; int xx[2] = {x0, x0 + 1};
        float wyv[2] = {1.f - wy, wy}; float wxv[2] = {1.f - wx, wx};
        uint base = (uint)t * 8;
        #pragma unroll
        for (int ci = 0; ci < 2; ci++)
        #pragma unroll
        for (int cj = 0; cj < 2; cj++) {
            int yv = yy[ci], xv = xx[cj];
            bool val = ((unsigned)yv < 128u) && ((unsigned)xv < 128u);
            int ycl = min(max(yv, 0), 127), xcl = min(max(xv, 0), 127);
            int slot = ci * 2 + cj;
            s_aw[base + slot * 2]     = (uint)((ycl * 128 + xcl) * 64);
            s_aw[base + slot * 2 + 1] = __float_as_uint(val ? wyv[ci] * wxv[cj] : 0.f);
        }
    }
    __syncthreads();

    int wv = t >> 6, lane = t & 63;
    // phase 1: coalesced NHWC gather, lane = channel; wave wv owns px 4wv..4wv+3
    {
        const ushort* xnb = xnh + (size_t)b * HW * 64;
        int dbase = wv * 4672 + 2 * lane;          // bytes into s_a (4672 = 4*584*2)
        int awbase = wv * 288;                     // uints
        #pragma unroll
        for (int pp = 0; pp < 4; pp++) {
            #pragma unroll
            for (int tp = 0; tp < 9; tp++) {
                const uint4 q0 = *reinterpret_cast<const uint4*>(&s_aw[awbase + (pp * 9 + tp) * 8]);
                const uint4 q1 = *reinterpret_cast<const uint4*>(&s_aw[awbase + (pp * 9 + tp) * 8 + 4]);
                ushort u0 = xnb[q0.x + lane];
                ushort u1 = xnb[q0.z + lane];
                ushort u2 = xnb[q1.x + lane];
                ushort u3 = xnb[q1.z + lane];
                float acc = __uint_as_float(q0.y) * __uint_as_float((uint)u0 << 16);
                acc = fmaf(__uint_as_float(q0.w), __uint_as_float((uint)u1 << 16), acc);
                acc = fmaf(__uint_as_float(q1.y), __uint_as_float((uint)u2 << 16), acc);
                acc = fmaf(__uint_as_float(q1.w), __uint_as_float((uint)u3 << 16), acc);
                *reinterpret_cast<ushort*>(reinterpret_cast<char*>(s_a) + dbase + pp * 1168 + tp * 128)
                    = f32_to_bf16(acc);
            }
        }
    }
    __syncthreads();

    // phase 2: MFMA. wave = (ph = px-half, wo = oc-block); D[oc][px]
    int wo = wv & 3, ph = wv >> 2;
    int g = lane >> 4, li = lane & 15;
    f32x4 acc;
    const float* bp = bias + wo * 16 + g * 4;
    acc.x = bp[0]; acc.y = bp[1]; acc.z = bp[2]; acc.w = bp[3];
    const short8* ap = reinterpret_cast<const short8*>(wA) + (wo * 18) * 64 + lane;
    const ushort* sp = s_a + (ph * 16 + li) * 584 + g * 8;
    #pragma unroll
    for (int kk = 0; kk < 18; kk++) {
        short8 af = ap[kk * 64];                                   // weights (arg0)
        short8 bf = *reinterpret_cast<const short8*>(sp + kk * 32); // samples (arg1)
        acc = __builtin_amdgcn_mfma_f32_16x16x32_bf16(af, bf, acc, 0, 0, 0);
    }
    size_t ybase = ((size_t)(b * 64 + wo * 16 + g * 4)) * HW + h * Ww + w0 + ph * 16 + li;
    y[ybase]           = acc.x;
    y[ybase + HW]      = acc.y;
    y[ybase + 2 * HW]  = acc.z;
    y[ybase + 3 * HW]  = acc.w;
}

// ---- GroupNorm(1): stage A partial sums ----
__global__ __launch_bounds__(256)
void gn_partial_kernel(const float* __restrict__ y, float* __restrict__ part) {
    int b = blockIdx.x >> 6;
    int blk = blockIdx.x & 63;
    const float* yb = y + (size_t)b * Cc * HW;
    const int n = Cc * HW;
    float s = 0.f, s2 = 0.f;
    for (int i = blk * 256 + threadIdx.x; i < n; i += 64 * 256) {
        float v = yb[i];
        s += v; s2 += v * v;
    }
    for (int o = 32; o > 0; o >>= 1) {
        s  += __shfl_down(s, o);
        s2 += __shfl_down(s2, o);
    }
    __shared__ float ls[4][2];
    int wave = threadIdx.x >> 6, lane = threadIdx.x & 63;
    if (lane == 0) { ls[wave][0] = s; ls[wave][1] = s2; }
    __syncthreads();
    if (threadIdx.x == 0) {
        float a = 0.f, c = 0.f;
        for (int i = 0; i < 4; i++) { a += ls[i][0]; c += ls[i][1]; }
        part[blockIdx.x * 2]     = a;
        part[blockIdx.x * 2 + 1] = c;
    }
}

// ---- GroupNorm(1): stage B ----
__global__ void gn_final_kernel(const float* __restrict__ part, float* __restrict__ stats) {
    int b = blockIdx.x;
    int l = threadIdx.x;
    float s  = part[(b * 64 + l) * 2];
    float s2 = part[(b * 64 + l) * 2 + 1];
    for (int o = 32; o > 0; o >>= 1) {
        s  += __shfl_down(s, o);
        s2 += __shfl_down(s2, o);
    }
    if (l == 0) {
        const float n = (float)(Cc * HW);
        float m = s / n;
        float var = s2 / n - m * m;
        stats[b * 2]     = m;
        stats[b * 2 + 1] = rsqrtf(var + EPSf);
    }
}

// ---- normalize + ReLU + residual ----
__global__ __launch_bounds__(256)
void gn_finalize_kernel(const float* __restrict__ y, const float* __restrict__ res,
                        const float* __restrict__ g, const float* __restrict__ be,
                        const float* __restrict__ stats, float* __restrict__ out) {
    int idx = blockIdx.x * 256 + threadIdx.x;
    int c = (idx >> 14) & 63;
    int b = idx >> 20;
    float m = stats[b * 2], rs = stats[b * 2 + 1];
    float v = (y[idx] - m) * rs * g[c] + be[c];
    out[idx] = fmaxf(v, 0.f) + res[idx];
}

extern "C" void kernel_launch(void* const* d_in, const int* in_sizes, int n_in,
                              void* d_out, int out_size, void* d_ws, size_t ws_size,
                              hipStream_t stream) {
    const float* x   = (const float*)d_in[0];
    const float* w1  = (const float*)d_in[1];
    const float* b1  = (const float*)d_in[2];
    const float* ow1 = (const float*)d_in[3];
    const float* ob1 = (const float*)d_in[4];
    const float* g1  = (const float*)d_in[5];
    const float* be1 = (const float*)d_in[6];
    const float* w2  = (const float*)d_in[7];
    const float* b2  = (const float*)d_in[8];
    const float* ow2 = (const float*)d_in[9];
    const float* ob2 = (const float*)d_in[10];
    const float* g2  = (const float*)d_in[11];
    const float* be2 = (const float*)d_in[12];
    float* out = (float*)d_out;

    float* ws    = (float*)d_ws;
    float* off   = ws;                                   // 1,179,648 f
    float* ybuf  = off + (size_t)Bz * 18 * HW;           // 4,194,304 f
    float* h1    = ybuf + (size_t)Bz * Cc * HW;          // 4,194,304 f
    ushort* xnh  = (ushort*)(h1 + (size_t)Bz * Cc * HW); // 4,194,304 bf16
    ushort* hnh  = xnh + (size_t)Bz * HW * 64;           // 4,194,304 bf16
    ushort* wA1  = hnh + (size_t)Bz * HW * 64;           // 36,864 bf16
    ushort* wA2  = wA1 + 36864;                          // 36,864 bf16
    float* part  = (float*)(wA2 + 36864);                // 512 f
    float* stats = part + 512;                           // 8 f

    wfrag_kernel<<<(2 * 36864 + 255) / 256, 256, 0, stream>>>(w1, w2, wA1, wA2);
    nhwc_kernel<<<Bz * (HW / 64), 256, 0, stream>>>(x, xnh);

    // block 1: deform_conv -> GN -> relu -> +x
    offconv_kernel<<<Bz * Hh * (Ww / 64), 256, 0, stream>>>(x, ow1, ob1, off);
    deform_mfma_kernel<<<Bz * Hh * (Ww / 32), 512, 0, stream>>>(xnh, wA1, b1, off, ybuf);
    gn_partial_kernel<<<256, 256, 0, stream>>>(ybuf, part);
    gn_final_kernel<<<4, 64, 0, stream>>>(part, stats);
    gn_finalize_kernel<<<Bz * Cc * HW / 256, 256, 0, stream>>>(ybuf, x, g1, be1, stats, h1);

    // block 2: deform_conv -> GN -> relu -> +h1
    nhwc_kernel<<<Bz * (HW / 64), 256, 0, stream>>>(h1, hnh);
    offconv_kernel<<<Bz * Hh * (Ww / 64), 256, 0, stream>>>(h1, ow2, ob2, off);
    deform_mfma_kernel<<<Bz * Hh * (Ww / 32), 512, 0, stream>>>(hnh, wA2, b2, off, ybuf);
    gn_partial_kernel<<<256, 256, 0, stream>>>(ybuf, part);
    gn_final_kernel<<<4, 64, 0, stream>>>(part, stats);
    gn_finalize_kernel<<<Bz * Cc * HW / 256, 256, 0, stream>>>(ybuf, h1, g2, be2, stats, out);
}

// Round 4
// 182.526 us; speedup vs baseline: 5.2365x; 1.7329x over previous
//
#include <hip/hip_runtime.h>
#include <math.h>

constexpr int Bz = 4, Cc = 64, Hh = 128, Ww = 128, Kk = 9;
constexpr int HW = Hh * Ww;              // 16384
constexpr float EPSf = 1e-5f;
constexpr int CK = Cc * Kk;              // 576

typedef __attribute__((ext_vector_type(8))) short short8;
typedef __attribute__((ext_vector_type(4))) float f32x4;

__device__ __forceinline__ ushort f32_to_bf16(float f) {
    uint u = __float_as_uint(f);
    return (ushort)((u + 0x7fffu + ((u >> 16) & 1u)) >> 16);   // RNE
}

// ---- deform weight fragments: wA[(wo*18+kk)*64+l][j] = w[oc][c][tap] (bf16) ----
// oc = wo*16 + (l&15); kidx = kk*32 + (l>>4)*8 + j; tap = kidx>>6; c = kidx&63
__global__ void wfrag_kernel(const float* __restrict__ w1, const float* __restrict__ w2,
                             ushort* __restrict__ wA1, ushort* __restrict__ wA2) {
    int tid = blockIdx.x * 256 + threadIdx.x;     // 2 * 36864
    if (tid >= 2 * 36864) return;
    const float* w = (tid < 36864) ? w1 : w2;
    ushort* dst = (tid < 36864) ? wA1 : wA2;
    int e = tid % 36864;
    int j = e & 7, l = (e >> 3) & 63, kk = (e >> 9) % 18, wo = e / 9216;
    int oc = wo * 16 + (l & 15);
    int kidx = kk * 32 + ((l >> 4) * 8) + j;
    int tap = kidx >> 6, c = kidx & 63;
    dst[e] = f32_to_bf16(w[oc * CK + c * 9 + tap]);
}

// ---- offset-conv weight fragments: same scheme, 2 oc-tiles, oc>=18 -> 0 ----
__global__ void owfrag_kernel(const float* __restrict__ ow1, const float* __restrict__ ow2,
                              ushort* __restrict__ o1, ushort* __restrict__ o2) {
    int tid = blockIdx.x * 256 + threadIdx.x;     // 2 * 18432
    if (tid >= 2 * 18432) return;
    const float* ow = (tid < 18432) ? ow1 : ow2;
    ushort* dst = (tid < 18432) ? o1 : o2;
    int e = tid % 18432;
    int j = e & 7, l = (e >> 3) & 63, kk = (e >> 9) % 18, wo = e / 9216;
    int oc = wo * 16 + (l & 15);
    int kidx = kk * 32 + ((l >> 4) * 8) + j;
    int tap = kidx >> 6, c = kidx & 63;
    dst[e] = (oc < 18) ? f32_to_bf16(ow[oc * CK + c * 9 + tap]) : (ushort)0;
}

// ---- NCHW fp32 -> NHWC bf16 (tiled transpose) ----
__global__ __launch_bounds__(256)
void nhwc_kernel(const float* __restrict__ src, ushort* __restrict__ dst) {
    __shared__ float s_t[64][65];
    int blk = blockIdx.x;                 // Bz * (HW/64) = 1024
    int p0 = (blk & 255) * 64;
    int b = blk >> 8;
    int t = threadIdx.x;
    int tp = t & 63;
    #pragma unroll
    for (int i = 0; i < 16; i++) {
        int c = i * 4 + (t >> 6);
        s_t[c][tp] = src[((size_t)(b * 64 + c)) * HW + p0 + tp];
    }
    __syncthreads();
    #pragma unroll
    for (int i = 0; i < 16; i++) {
        int pl = i * 4 + (t >> 6);
        dst[((size_t)b * HW + p0 + pl) * 64 + tp] = f32_to_bf16(s_t[tp][pl]);
    }
}

// ---- fused offset-conv + deformable conv, block = 32 px of one (b,h) row ----
__global__ __launch_bounds__(512, 3)
void deform_fused_kernel(const ushort* __restrict__ xnh, const ushort* __restrict__ wA,
                         const ushort* __restrict__ owA, const float* __restrict__ bias,
                         const float* __restrict__ obias, float* __restrict__ y) {
    __shared__ __align__(16) ushort s_a[32 * 584];    // A[px][tap*64+c] bf16, +8 pad
    __shared__ __align__(16) uint   s_aw[32 * 9 * 8]; // per (px,tap): 4x{addr,wgt}
    __shared__ float off_s[32][18];                   // offsets for these 32 px

    int blk = blockIdx.x;            // Bz*Hh*(Ww/32) = 2048
    int wt = blk & 3;
    int h  = (blk >> 2) & 127;
    int b  = blk >> 9;
    int w0 = wt * 32;
    int t = threadIdx.x;
    int wv = t >> 6, lane = t & 63;
    const ushort* xnb = xnh + (size_t)b * HW * 64;

    // ---- phase A: offset conv via MFMA (4 waves; B-frag direct from global) ----
    if (wv < 4) {
        int wo = wv & 1, ph = wv >> 1;
        int g = lane >> 4, li = lane & 15;
        int px = ph * 16 + li;
        f32x4 oacc;
        #pragma unroll
        for (int r = 0; r < 4; r++) {
            int oc = wo * 16 + g * 4 + r;
            oacc[r] = (oc < 18) ? obias[oc] : 0.f;
        }
        const short8* owp = reinterpret_cast<const short8*>(owA) + (wo * 18) * 64 + lane;
        #pragma unroll
        for (int kk = 0; kk < 18; kk++) {
            int tap = kk >> 1;
            int ky = tap / 3 - 1, kx = tap - (tap / 3) * 3 - 1;
            int c0 = (kk & 1) * 32 + g * 8;
            int gy = h + ky, gx = w0 + px + kx;
            bool valid = ((unsigned)gy < 128u) && ((unsigned)gx < 128u);
            short8 bf = {0, 0, 0, 0, 0, 0, 0, 0};
            if (valid)
                bf = *reinterpret_cast<const short8*>(&xnb[(((gy << 7) + gx) << 6) + c0]);
            short8 af = owp[kk * 64];
            oacc = __builtin_amdgcn_mfma_f32_16x16x32_bf16(af, bf, oacc, 0, 0, 0);
        }
        #pragma unroll
        for (int r = 0; r < 4; r++) {
            int oc = wo * 16 + g * 4 + r;
            if (oc < 18) off_s[px][oc] = oacc[r];
        }
    }
    __syncthreads();

    // ---- phase 0: bilinear coords -> clamped corner addrs + folded weights ----
    if (t < 288) {
        int px = t / 9, k = t - px * 9;
        int ky = k / 3 - 1, kx = k - (k / 3) * 3 - 1;
        float ody = off_s[px][2 * k];
        float odx = off_s[px][2 * k + 1];
        float cy = (float)(h + ky) + ody;
        float cx = (float)(w0 + px + kx) + odx;
        float fy = floorf(cy), fx = floorf(cx);
        float wy = cy - fy, wx = cx - fx;
        int y0 = (int)fy, x0 = (int)fx;
        int yy[2] = {y0, y0 + 1}; int xx[2] = {x0, x0 + 1};
        float wyv[2] = {1.f - wy, wy}; float wxv[2] = {1.f - wx, wx};
        uint base = (uint)t * 8;
        #pragma unroll
        for (int ci = 0; ci < 2; ci++)
        #pragma unroll
        for (int cj = 0; cj < 2; cj++) {
            int yv = yy[ci], xv = xx[cj];
            bool val = ((unsigned)yv < 128u) && ((unsigned)xv < 128u);
            int ycl = min(max(yv, 0), 127), xcl = min(max(xv, 0), 127);
            int slot = ci * 2 + cj;
            s_aw[base + slot * 2]     = (uint)((ycl * 128 + xcl) * 64);
            s_aw[base + slot * 2 + 1] = __float_as_uint(val ? wyv[ci] * wxv[cj] : 0.f);
        }
    }
    __syncthreads();

    // ---- phase 1: coalesced NHWC gather, lane = channel ----
    {
        int dbase = wv * 4672 + 2 * lane;          // bytes into s_a (4672 = 4*584*2)
        int awbase = wv * 288;                     // uints
        #pragma unroll
        for (int pp = 0; pp < 4; pp++) {
            #pragma unroll
            for (int tp = 0; tp < 9; tp++) {
                const uint4 q0 = *reinterpret_cast<const uint4*>(&s_aw[awbase + (pp * 9 + tp) * 8]);
                const uint4 q1 = *reinterpret_cast<const uint4*>(&s_aw[awbase + (pp * 9 + tp) * 8 + 4]);
                ushort u0 = xnb[q0.x + lane];
                ushort u1 = xnb[q0.z + lane];
                ushort u2 = xnb[q1.x + lane];
                ushort u3 = xnb[q1.z + lane];
                float acc = __uint_as_float(q0.y) * __uint_as_float((uint)u0 << 16);
                acc = fmaf(__uint_as_float(q0.w), __uint_as_float((uint)u1 << 16), acc);
                acc = fmaf(__uint_as_float(q1.y), __uint_as_float((uint)u2 << 16), acc);
                acc = fmaf(__uint_as_float(q1.w), __uint_as_float((uint)u3 << 16), acc);
                *reinterpret_cast<ushort*>(reinterpret_cast<char*>(s_a) + dbase + pp * 1168 + tp * 128)
                    = f32_to_bf16(acc);
            }
        }
    }
    __syncthreads();

    // ---- phase 2: deform MFMA. wave = (ph, wo); D[oc][px] ----
    int wo = wv & 3, ph = wv >> 2;
    int g = lane >> 4, li = lane & 15;
    f32x4 acc;
    const float* bp = bias + wo * 16 + g * 4;
    acc.x = bp[0]; acc.y = bp[1]; acc.z = bp[2]; acc.w = bp[3];
    const short8* ap = reinterpret_cast<const short8*>(wA) + (wo * 18) * 64 + lane;
    const ushort* sp = s_a + (ph * 16 + li) * 584 + g * 8;
    #pragma unroll
    for (int kk = 0; kk < 18; kk++) {
        short8 af = ap[kk * 64];                                    // weights (arg0)
        short8 bf = *reinterpret_cast<const short8*>(sp + kk * 32); // samples (arg1)
        acc = __builtin_amdgcn_mfma_f32_16x16x32_bf16(af, bf, acc, 0, 0, 0);
    }
    size_t ybase = ((size_t)(b * 64 + wo * 16 + g * 4)) * HW + h * Ww + w0 + ph * 16 + li;
    y[ybase]           = acc.x;
    y[ybase + HW]      = acc.y;
    y[ybase + 2 * HW]  = acc.z;
    y[ybase + 3 * HW]  = acc.w;
}

// ---- GroupNorm(1): stage A partial sums ----
__global__ __launch_bounds__(256)
void gn_partial_kernel(const float* __restrict__ y, float* __restrict__ part) {
    int b = blockIdx.x >> 6;
    int blk = blockIdx.x & 63;
    const float* yb = y + (size_t)b * Cc * HW;
    const int n = Cc * HW;
    float s = 0.f, s2 = 0.f;
    for (int i = blk * 256 + threadIdx.x; i < n; i += 64 * 256) {
        float v = yb[i];
        s += v; s2 += v * v;
    }
    for (int o = 32; o > 0; o >>= 1) {
        s  += __shfl_down(s, o);
        s2 += __shfl_down(s2, o);
    }
    __shared__ float ls[4][2];
    int wave = threadIdx.x >> 6, lane = threadIdx.x & 63;
    if (lane == 0) { ls[wave][0] = s; ls[wave][1] = s2; }
    __syncthreads();
    if (threadIdx.x == 0) {
        float a = 0.f, c = 0.f;
        for (int i = 0; i < 4; i++) { a += ls[i][0]; c += ls[i][1]; }
        part[blockIdx.x * 2]     = a;
        part[blockIdx.x * 2 + 1] = c;
    }
}

// ---- GroupNorm(1): stage B ----
__global__ void gn_final_kernel(const float* __restrict__ part, float* __restrict__ stats) {
    int b = blockIdx.x;
    int l = threadIdx.x;
    float s  = part[(b * 64 + l) * 2];
    float s2 = part[(b * 64 + l) * 2 + 1];
    for (int o = 32; o > 0; o >>= 1) {
        s  += __shfl_down(s, o);
        s2 += __shfl_down(s2, o);
    }
    if (l == 0) {
        const float n = (float)(Cc * HW);
        float m = s / n;
        float var = s2 / n - m * m;
        stats[b * 2]     = m;
        stats[b * 2 + 1] = rsqrtf(var + EPSf);
    }
}

// ---- normalize + ReLU + residual ----
__global__ __launch_bounds__(256)
void gn_finalize_kernel(const float* __restrict__ y, const float* __restrict__ res,
                        const float* __restrict__ g, const float* __restrict__ be,
                        const float* __restrict__ stats, float* __restrict__ out) {
    int idx = blockIdx.x * 256 + threadIdx.x;
    int c = (idx >> 14) & 63;
    int b = idx >> 20;
    float m = stats[b * 2], rs = stats[b * 2 + 1];
    float v = (y[idx] - m) * rs * g[c] + be[c];
    out[idx] = fmaxf(v, 0.f) + res[idx];
}

extern "C" void kernel_launch(void* const* d_in, const int* in_sizes, int n_in,
                              void* d_out, int out_size, void* d_ws, size_t ws_size,
                              hipStream_t stream) {
    const float* x   = (const float*)d_in[0];
    const float* w1  = (const float*)d_in[1];
    const float* b1  = (const float*)d_in[2];
    const float* ow1 = (const float*)d_in[3];
    const float* ob1 = (const float*)d_in[4];
    const float* g1  = (const float*)d_in[5];
    const float* be1 = (const float*)d_in[6];
    const float* w2  = (const float*)d_in[7];
    const float* b2  = (const float*)d_in[8];
    const float* ow2 = (const float*)d_in[9];
    const float* ob2 = (const float*)d_in[10];
    const float* g2  = (const float*)d_in[11];
    const float* be2 = (const float*)d_in[12];
    float* out = (float*)d_out;

    float* ws    = (float*)d_ws;
    float* ybuf  = ws;                                   // 4,194,304 f
    float* h1    = ybuf + (size_t)Bz * Cc * HW;          // 4,194,304 f
    ushort* xnh  = (ushort*)(h1 + (size_t)Bz * Cc * HW); // 4,194,304 bf16
    ushort* hnh  = xnh + (size_t)Bz * HW * 64;           // 4,194,304 bf16
    ushort* wA1  = hnh + (size_t)Bz * HW * 64;           // 36,864 bf16
    ushort* wA2  = wA1 + 36864;                          // 36,864 bf16
    ushort* owA1 = wA2 + 36864;                          // 18,432 bf16
    ushort* owA2 = owA1 + 18432;                         // 18,432 bf16
    float* part  = (float*)(owA2 + 18432);               // 512 f
    float* stats = part + 512;                           // 8 f

    wfrag_kernel<<<(2 * 36864 + 255) / 256, 256, 0, stream>>>(w1, w2, wA1, wA2);
    owfrag_kernel<<<(2 * 18432 + 255) / 256, 256, 0, stream>>>(ow1, ow2, owA1, owA2);
    nhwc_kernel<<<Bz * (HW / 64), 256, 0, stream>>>(x, xnh);

    // block 1: offset-conv + deform_conv (fused) -> GN -> relu -> +x
    deform_fused_kernel<<<Bz * Hh * (Ww / 32), 512, 0, stream>>>(xnh, wA1, owA1, b1, ob1, ybuf);
    gn_partial_kernel<<<256, 256, 0, stream>>>(ybuf, part);
    gn_final_kernel<<<4, 64, 0, stream>>>(part, stats);
    gn_finalize_kernel<<<Bz * Cc * HW / 256, 256, 0, stream>>>(ybuf, x, g1, be1, stats, h1);

    // block 2: same, residual on h1
    nhwc_kernel<<<Bz * (HW / 64), 256, 0, stream>>>(h1, hnh);
    deform_fused_kernel<<<Bz * Hh * (Ww / 32), 512, 0, stream>>>(hnh, wA2, owA2, b2, ob2, ybuf);
    gn_partial_kernel<<<256, 256, 0, stream>>>(ybuf, part);
    gn_final_kernel<<<4, 64, 0, stream>>>(part, stats);
    gn_finalize_kernel<<<Bz * Cc * HW / 256, 256, 0, stream>>>(ybuf, h1, g2, be2, stats, out);
}

// Round 5
// 124.923 us; speedup vs baseline: 7.6511x; 1.4611x over previous
//
#include <hip/hip_runtime.h>
#include <hip/hip_bf16.h>
#include <math.h>

constexpr int Bz = 4, Cc = 64, Hh = 128, Ww = 128, Kk = 9;
constexpr int HW = Hh * Ww;              // 16384
constexpr float EPSf = 1e-5f;
constexpr int CK = Cc * Kk;              // 576

typedef __attribute__((ext_vector_type(8))) short short8;
typedef __attribute__((ext_vector_type(4))) float f32x4;

__device__ __forceinline__ ushort f32_to_bf16(float f) {
    uint u = __float_as_uint(f);
    return (ushort)((u + 0x7fffu + ((u >> 16) & 1u)) >> 16);   // RNE
}

// ---- deform weight fragments: wA[(wo*18+kk)*64+l][j] = w[oc][c][tap] (bf16) ----
__global__ void wfrag_kernel(const float* __restrict__ w1, const float* __restrict__ w2,
                             ushort* __restrict__ wA1, ushort* __restrict__ wA2) {
    int tid = blockIdx.x * 256 + threadIdx.x;     // 2 * 36864
    if (tid >= 2 * 36864) return;
    const float* w = (tid < 36864) ? w1 : w2;
    ushort* dst = (tid < 36864) ? wA1 : wA2;
    int e = tid % 36864;
    int j = e & 7, l = (e >> 3) & 63, kk = (e >> 9) % 18, wo = e / 9216;
    int oc = wo * 16 + (l & 15);
    int kidx = kk * 32 + ((l >> 4) * 8) + j;
    int tap = kidx >> 6, c = kidx & 63;
    dst[e] = f32_to_bf16(w[oc * CK + c * 9 + tap]);
}

// ---- offset-conv weight fragments: same scheme, 2 oc-tiles, oc>=18 -> 0 ----
__global__ void owfrag_kernel(const float* __restrict__ ow1, const float* __restrict__ ow2,
                              ushort* __restrict__ o1, ushort* __restrict__ o2) {
    int tid = blockIdx.x * 256 + threadIdx.x;     // 2 * 18432
    if (tid >= 2 * 18432) return;
    const float* ow = (tid < 18432) ? ow1 : ow2;
    ushort* dst = (tid < 18432) ? o1 : o2;
    int e = tid % 18432;
    int j = e & 7, l = (e >> 3) & 63, kk = (e >> 9) % 18, wo = e / 9216;
    int oc = wo * 16 + (l & 15);
    int kidx = kk * 32 + ((l >> 4) * 8) + j;
    int tap = kidx >> 6, c = kidx & 63;
    dst[e] = (oc < 18) ? f32_to_bf16(ow[oc * CK + c * 9 + tap]) : (ushort)0;
}

// ---- NCHW fp32 -> NHWC bf16 (tiled transpose), for x only ----
__global__ __launch_bounds__(256)
void nhwc_kernel(const float* __restrict__ src, ushort* __restrict__ dst) {
    __shared__ float s_t[64][65];
    int blk = blockIdx.x;                 // Bz * (HW/64) = 1024
    int p0 = (blk & 255) * 64;
    int b = blk >> 8;
    int t = threadIdx.x;
    int tp = t & 63;
    #pragma unroll
    for (int i = 0; i < 16; i++) {
        int c = i * 4 + (t >> 6);
        s_t[c][tp] = src[((size_t)(b * 64 + c)) * HW + p0 + tp];
    }
    __syncthreads();
    #pragma unroll
    for (int i = 0; i < 16; i++) {
        int pl = i * 4 + (t >> 6);
        dst[((size_t)b * HW + p0 + pl) * 64 + tp] = f32_to_bf16(s_t[tp][pl]);
    }
}

// ---- fused offset-conv + deformable conv + GN partial reduce ----
// block = 32 px of one (b,h) row, 512 threads
__global__ __launch_bounds__(512, 3)
void deform_fused_kernel(const ushort* __restrict__ xnh, const ushort* __restrict__ wA,
                         const ushort* __restrict__ owA, const float* __restrict__ bias,
                         const float* __restrict__ obias, float* __restrict__ y,
                         float* __restrict__ part) {
    __shared__ __align__(16) ushort s_a[32 * 584];    // A[px][tap*64+c] bf16, +8 pad
    __shared__ __align__(16) uint   s_aw[32 * 9 * 8]; // per (px,tap): 4x{byteaddr,wgt}
    __shared__ float off_s2[2][32][18];               // offsets, K-split halves

    int blk = blockIdx.x;            // Bz*Hh*(Ww/32) = 2048
    int wt = blk & 3;
    int h  = (blk >> 2) & 127;
    int b  = blk >> 9;
    int w0 = wt * 32;
    int t = threadIdx.x;
    int wv = t >> 6, lane = t & 63;
    const ushort* xnb = xnh + (size_t)b * HW * 64;

    // ---- phase A: offset conv via MFMA; all 8 waves (K split in halves) ----
    {
        int wo = wv & 1, ph = (wv >> 1) & 1, kh = wv >> 2;
        int g = lane >> 4, li = lane & 15;
        int px = ph * 16 + li;
        f32x4 oacc;
        #pragma unroll
        for (int r = 0; r < 4; r++) {
            int oc = wo * 16 + g * 4 + r;
            oacc[r] = (kh == 0 && oc < 18) ? obias[oc] : 0.f;
        }
        const short8* owp = reinterpret_cast<const short8*>(owA) + (wo * 18) * 64 + lane;
        #pragma unroll
        for (int kki = 0; kki < 9; kki++) {
            int kk = kh * 9 + kki;
            int tap = kk >> 1;
            int ky = tap / 3 - 1, kx = tap - (tap / 3) * 3 - 1;
            int c0 = (kk & 1) * 32 + g * 8;
            int gy = h + ky, gx = w0 + px + kx;
            bool valid = ((unsigned)gy < 128u) && ((unsigned)gx < 128u);
            short8 bf = {0, 0, 0, 0, 0, 0, 0, 0};
            if (valid)
                bf = *reinterpret_cast<const short8*>(&xnb[(((gy << 7) + gx) << 6) + c0]);
            short8 af = owp[kk * 64];
            oacc = __builtin_amdgcn_mfma_f32_16x16x32_bf16(af, bf, oacc, 0, 0, 0);
        }
        #pragma unroll
        for (int r = 0; r < 4; r++) {
            int oc = wo * 16 + g * 4 + r;
            if (oc < 18) off_s2[kh][px][oc] = oacc[r];
        }
    }
    __syncthreads();

    // ---- phase 0: bilinear coords -> clamped corner byte-addrs + folded wgts ----
    if (t < 288) {
        int px = t / 9, k = t - px * 9;
        int ky = k / 3 - 1, kx = k - (k / 3) * 3 - 1;
        float ody = off_s2[0][px][2 * k]     + off_s2[1][px][2 * k];
        float odx = off_s2[0][px][2 * k + 1] + off_s2[1][px][2 * k + 1];
        float cy = (float)(h + ky) + ody;
        float cx = (float)(w0 + px + kx) + odx;
        float fy = floorf(cy), fx = floorf(cx);
        float wy = cy - fy, wx = cx - fx;
        int y0 = (int)fy, x0 = (int)fx;
        int yy[2] = {y0, y0 + 1}; int xx[2] = {x0, x0 + 1};
        float wyv[2] = {1.f - wy, wy}; float wxv[2] = {1.f - wx, wx};
        uint base = (uint)t * 8;
        #pragma unroll
        for (int ci = 0; ci < 2; ci++)
        #pragma unroll
        for (int cj = 0; cj < 2; cj++) {
            int yv = yy[ci], xv = xx[cj];
            bool val = ((unsigned)yv < 128u) && ((unsigned)xv < 128u);
            int ycl = min(max(yv, 0), 127), xcl = min(max(xv, 0), 127);
            int slot = ci * 2 + cj;
            s_aw[base + slot * 2]     = (uint)(((ycl << 7) + xcl) << 7);  // byte addr
            s_aw[base + slot * 2 + 1] = __float_as_uint(val ? wyv[ci] * wxv[cj] : 0.f);
        }
    }
    __syncthreads();

    // ---- phase 1: packed gather, 2 channels/lane, 2 px-halves/wave ----
    {
        int half = lane >> 5, cl = lane & 31;
        int cl4 = cl << 2;
        int vbase = wv * 288 + half * 72;             // uint index into s_aw
        int wbase = (4 * wv + half) * 1168 + cl4;     // byte offset into s_a
        const char* xnc = reinterpret_cast<const char*>(xnb);
        char* s_ab = reinterpret_cast<char*>(s_a);
        #pragma unroll
        for (int pp = 0; pp < 2; pp++) {
            #pragma unroll
            for (int tp = 0; tp < 9; tp++) {
                int e = vbase + pp * 144 + tp * 8;
                uint4 q0 = *reinterpret_cast<const uint4*>(&s_aw[e]);
                uint4 q1 = *reinterpret_cast<const uint4*>(&s_aw[e + 4]);
                uint u0 = *reinterpret_cast<const uint*>(xnc + (q0.x + cl4));
                uint u1 = *reinterpret_cast<const uint*>(xnc + (q0.z + cl4));
                uint u2 = *reinterpret_cast<const uint*>(xnc + (q1.x + cl4));
                uint u3 = *reinterpret_cast<const uint*>(xnc + (q1.z + cl4));
                float w00 = __uint_as_float(q0.y), w01 = __uint_as_float(q0.w);
                float w10 = __uint_as_float(q1.y), w11 = __uint_as_float(q1.w);
                float lo = w00 * __uint_as_float(u0 << 16);
                float hi = w00 * __uint_as_float(u0 & 0xffff0000u);
                lo = fmaf(w01, __uint_as_float(u1 << 16), lo);
                hi = fmaf(w01, __uint_as_float(u1 & 0xffff0000u), hi);
                lo = fmaf(w10, __uint_as_float(u2 << 16), lo);
                hi = fmaf(w10, __uint_as_float(u2 & 0xffff0000u), hi);
                lo = fmaf(w11, __uint_as_float(u3 << 16), lo);
                hi = fmaf(w11, __uint_as_float(u3 & 0xffff0000u), hi);
                float2 pr; pr.x = lo; pr.y = hi;
                __hip_bfloat162 bb = __float22bfloat162_rn(pr);
                *reinterpret_cast<uint*>(s_ab + wbase + pp * 2336 + tp * 128)
                    = *reinterpret_cast<uint*>(&bb);
            }
        }
    }
    __syncthreads();

    // ---- phase 2: deform MFMA. wave = (ph, wo); D[oc][px] ----
    int wo = wv & 3, ph = wv >> 2;
    int g = lane >> 4, li = lane & 15;
    f32x4 acc;
    const float* bp = bias + wo * 16 + g * 4;
    acc.x = bp[0]; acc.y = bp[1]; acc.z = bp[2]; acc.w = bp[3];
    const short8* ap = reinterpret_cast<const short8*>(wA) + (wo * 18) * 64 + lane;
    const ushort* sp = s_a + (ph * 16 + li) * 584 + g * 8;
    #pragma unroll
    for (int kk = 0; kk < 18; kk++) {
        short8 af = ap[kk * 64];                                    // weights (arg0)
        short8 bf = *reinterpret_cast<const short8*>(sp + kk * 32); // samples (arg1)
        acc = __builtin_amdgcn_mfma_f32_16x16x32_bf16(af, bf, acc, 0, 0, 0);
    }
    size_t ybase = ((size_t)(b * 64 + wo * 16 + g * 4)) * HW + h * Ww + w0 + ph * 16 + li;
    y[ybase]           = acc.x;
    y[ybase + HW]      = acc.y;
    y[ybase + 2 * HW]  = acc.z;
    y[ybase + 3 * HW]  = acc.w;

    // ---- epilogue: GN partial sums for this block's 2048 values ----
    float s  = acc.x + acc.y + acc.z + acc.w;
    float s2 = acc.x * acc.x + acc.y * acc.y + acc.z * acc.z + acc.w * acc.w;
    #pragma unroll
    for (int o = 32; o > 0; o >>= 1) {
        s  += __shfl_down(s, o);
        s2 += __shfl_down(s2, o);
    }
    float* redbuf = reinterpret_cast<float*>(s_aw);   // s_aw is dead now
    if (lane == 0) { redbuf[wv * 2] = s; redbuf[wv * 2 + 1] = s2; }
    __syncthreads();
    if (t == 0) {
        float a = 0.f, c2 = 0.f;
        #pragma unroll
        for (int i = 0; i < 8; i++) { a += redbuf[i * 2]; c2 += redbuf[i * 2 + 1]; }
        part[blk * 2]     = a;
        part[blk * 2 + 1] = c2;
    }
}

// ---- GN final: reduce 512 block-partials per sample -> mean, rsqrt ----
__global__ void gn_final2_kernel(const float* __restrict__ part, float* __restrict__ stats) {
    int b = blockIdx.x;
    int t = threadIdx.x;                          // 256
    int i0 = (b * 512 + t) * 2, i1 = (b * 512 + 256 + t) * 2;
    float s  = part[i0]     + part[i1];
    float s2 = part[i0 + 1] + part[i1 + 1];
    #pragma unroll
    for (int o = 32; o > 0; o >>= 1) {
        s  += __shfl_down(s, o);
        s2 += __shfl_down(s2, o);
    }
    __shared__ float ls[4][2];
    int wave = t >> 6, lane = t & 63;
    if (lane == 0) { ls[wave][0] = s; ls[wave][1] = s2; }
    __syncthreads();
    if (t == 0) {
        float a = 0.f, c = 0.f;
        #pragma unroll
        for (int i = 0; i < 4; i++) { a += ls[i][0]; c += ls[i][1]; }
        const float n = (float)(Cc * HW);
        float m = a / n;
        float var = c / n - m * m;
        stats[b * 2]     = m;
        stats[b * 2 + 1] = rsqrtf(var + EPSf);
    }
}

// ---- block-1 finalize: normalize+ReLU+residual -> h1 (NCHW f32) + hnh (NHWC bf16) ----
__global__ __launch_bounds__(256)
void gn_fin1_kernel(const float* __restrict__ y, const float* __restrict__ res,
                    const float* __restrict__ g, const float* __restrict__ be,
                    const float* __restrict__ stats, float* __restrict__ h1,
                    ushort* __restrict__ hnh) {
    __shared__ float s_t[64][65];
    int blk = blockIdx.x;                 // Bz * (HW/64) = 1024
    int p0 = (blk & 255) * 64;
    int b = blk >> 8;
    int t = threadIdx.x;
    int tp = t & 63;
    float m = stats[b * 2], rs = stats[b * 2 + 1];
    #pragma unroll
    for (int i = 0; i < 16; i++) {
        int c = i * 4 + (t >> 6);
        size_t idx = ((size_t)(b * 64 + c)) * HW + p0 + tp;
        float v = (y[idx] - m) * rs * g[c] + be[c];
        v = fmaxf(v, 0.f) + res[idx];
        h1[idx] = v;
        s_t[c][tp] = v;
    }
    __syncthreads();
    #pragma unroll
    for (int i = 0; i < 16; i++) {
        int pl = i * 4 + (t >> 6);
        hnh[((size_t)b * HW + p0 + pl) * 64 + tp] = f32_to_bf16(s_t[tp][pl]);
    }
}

// ---- block-2 finalize: normalize + ReLU + residual -> out (float4) ----
__global__ __launch_bounds__(256)
void gn_fin2_kernel(const float* __restrict__ y, const float* __restrict__ res,
                    const float* __restrict__ g, const float* __restrict__ be,
                    const float* __restrict__ stats, float* __restrict__ out) {
    int idx = (blockIdx.x * 256 + threadIdx.x) * 4;   // B*C*H*W / 4 threads
    int c = (idx >> 14) & 63;
    int b = idx >> 20;
    float m = stats[b * 2], rs = stats[b * 2 + 1];
    float gc = g[c], bc = be[c];
    float4 yv = *reinterpret_cast<const float4*>(y + idx);
    float4 rv = *reinterpret_cast<const float4*>(res + idx);
    float4 o;
    o.x = fmaxf((yv.x - m) * rs * gc + bc, 0.f) + rv.x;
    o.y = fmaxf((yv.y - m) * rs * gc + bc, 0.f) + rv.y;
    o.z = fmaxf((yv.z - m) * rs * gc + bc, 0.f) + rv.z;
    o.w = fmaxf((yv.w - m) * rs * gc + bc, 0.f) + rv.w;
    *reinterpret_cast<float4*>(out + idx) = o;
}

extern "C" void kernel_launch(void* const* d_in, const int* in_sizes, int n_in,
                              void* d_out, int out_size, void* d_ws, size_t ws_size,
                              hipStream_t stream) {
    const float* x   = (const float*)d_in[0];
    const float* w1  = (const float*)d_in[1];
    const float* b1  = (const float*)d_in[2];
    const float* ow1 = (const float*)d_in[3];
    const float* ob1 = (const float*)d_in[4];
    const float* g1  = (const float*)d_in[5];
    const float* be1 = (const float*)d_in[6];
    const float* w2  = (const float*)d_in[7];
    const float* b2  = (const float*)d_in[8];
    const float* ow2 = (const float*)d_in[9];
    const float* ob2 = (const float*)d_in[10];
    const float* g2  = (const float*)d_in[11];
    const float* be2 = (const float*)d_in[12];
    float* out = (float*)d_out;

    float* ws    = (float*)d_ws;
    float* ybuf  = ws;                                   // 4,194,304 f
    float* h1    = ybuf + (size_t)Bz * Cc * HW;          // 4,194,304 f
    ushort* xnh  = (ushort*)(h1 + (size_t)Bz * Cc * HW); // 4,194,304 bf16
    ushort* hnh  = xnh + (size_t)Bz * HW * 64;           // 4,194,304 bf16
    ushort* wA1  = hnh + (size_t)Bz * HW * 64;           // 36,864 bf16
    ushort* wA2  = wA1 + 36864;                          // 36,864 bf16
    ushort* owA1 = wA2 + 36864;                          // 18,432 bf16
    ushort* owA2 = owA1 + 18432;                         // 18,432 bf16
    float* part  = (float*)(owA2 + 18432);               // 4096 f
    float* stats = part + 4096;                          // 8 f

    wfrag_kernel<<<(2 * 36864 + 255) / 256, 256, 0, stream>>>(w1, w2, wA1, wA2);
    owfrag_kernel<<<(2 * 18432 + 255) / 256, 256, 0, stream>>>(ow1, ow2, owA1, owA2);
    nhwc_kernel<<<Bz * (HW / 64), 256, 0, stream>>>(x, xnh);

    // block 1: offset-conv + deform_conv + GN-partial (fused) -> stats -> fin1
    deform_fused_kernel<<<Bz * Hh * (Ww / 32), 512, 0, stream>>>(xnh, wA1, owA1, b1, ob1, ybuf, part);
    gn_final2_kernel<<<Bz, 256, 0, stream>>>(part, stats);
    gn_fin1_kernel<<<Bz * (HW / 64), 256, 0, stream>>>(ybuf, x, g1, be1, stats, h1, hnh);

    // block 2: same, residual on h1, elementwise finalize to out
    deform_fused_kernel<<<Bz * Hh * (Ww / 32), 512, 0, stream>>>(hnh, wA2, owA2, b2, ob2, ybuf, part);
    gn_final2_kernel<<<Bz, 256, 0, stream>>>(part, stats);
    gn_fin2_kernel<<<Bz * Cc * HW / 1024, 256, 0, stream>>>(ybuf, h1, g2, be2, stats, out);
}

// Round 6
// 122.637 us; speedup vs baseline: 7.7937x; 1.0186x over previous
//
#include <hip/hip_runtime.h>
#include <hip/hip_bf16.h>
#include <math.h>

constexpr int Bz = 4, Cc = 64, Hh = 128, Ww = 128, Kk = 9;
constexpr int HW = Hh * Ww;              // 16384
constexpr float EPSf = 1e-5f;
constexpr int CK = Cc * Kk;              // 576

typedef __attribute__((ext_vector_type(8))) short short8;
typedef __attribute__((ext_vector_type(4))) float f32x4;

__device__ __forceinline__ ushort f32_to_bf16(float f) {
    uint u = __float_as_uint(f);
    return (ushort)((u + 0x7fffu + ((u >> 16) & 1u)) >> 16);   // RNE
}

// ---- weight fragments (deform + offset-conv) in one launch ----
// wA[(wo*18+kk)*64+l][j] = w[oc][c][tap]; oc = wo*16+(l&15);
// kidx = kk*32+(l>>4)*8+j; tap = kidx>>6; c = kidx&63. oc>=Cout -> 0.
__global__ void frag_kernel(const float* __restrict__ w1, const float* __restrict__ w2,
                            const float* __restrict__ ow1, const float* __restrict__ ow2,
                            ushort* __restrict__ wA1, ushort* __restrict__ wA2,
                            ushort* __restrict__ oA1, ushort* __restrict__ oA2) {
    int tid = blockIdx.x * 256 + threadIdx.x;     // 2*36864 + 2*18432 = 110592
    if (tid >= 110592) return;
    const float* src; ushort* dst; int e; int cout;
    if (tid < 36864)        { src = w1;  dst = wA1; e = tid;         cout = 64; }
    else if (tid < 73728)   { src = w2;  dst = wA2; e = tid - 36864; cout = 64; }
    else if (tid < 92160)   { src = ow1; dst = oA1; e = tid - 73728; cout = 18; }
    else                    { src = ow2; dst = oA2; e = tid - 92160; cout = 18; }
    int j = e & 7, l = (e >> 3) & 63, kk = (e >> 9) % 18, wo = e / 9216;
    int oc = wo * 16 + (l & 15);
    int kidx = kk * 32 + ((l >> 4) * 8) + j;
    int tap = kidx >> 6, c = kidx & 63;
    dst[e] = (oc < cout) ? f32_to_bf16(src[oc * CK + c * 9 + tap]) : (ushort)0;
}

// ---- NCHW fp32 -> NHWC bf16 (tiled transpose), for x only ----
__global__ __launch_bounds__(256)
void nhwc_kernel(const float* __restrict__ src, ushort* __restrict__ dst) {
    __shared__ float s_t[64][65];
    int blk = blockIdx.x;                 // Bz * (HW/64) = 1024
    int p0 = (blk & 255) * 64;
    int b = blk >> 8;
    int t = threadIdx.x;
    int tp = t & 63;
    #pragma unroll
    for (int i = 0; i < 16; i++) {
        int c = i * 4 + (t >> 6);
        s_t[c][tp] = src[((size_t)(b * 64 + c)) * HW + p0 + tp];
    }
    __syncthreads();
    #pragma unroll
    for (int i = 0; i < 16; i++) {
        int pl = i * 4 + (t >> 6);
        dst[((size_t)b * HW + p0 + pl) * 64 + tp] = f32_to_bf16(s_t[tp][pl]);
    }
}

// ---- fused offset-conv + deformable conv + GN partial reduce ----
// block = 32 px of one (b,h) row, 512 threads
__global__ __launch_bounds__(512, 6)
void deform_fused_kernel(const ushort* __restrict__ xnh, const ushort* __restrict__ wA,
                         const ushort* __restrict__ owA, const float* __restrict__ bias,
                         const float* __restrict__ obias, float* __restrict__ y,
                         float* __restrict__ part) {
    __shared__ __align__(16) ushort s_a[32 * 584];    // A[px][tap*64+c] bf16, +8 pad
    __shared__ __align__(16) uint   s_aw[32 * 9 * 8]; // per (px,tap): 4x{byteaddr,wgt}
    // off_s2 aliases s_a: phase A writes it, phase 0 reads it, THEN phase 1
    // overwrites s_a (sync-separated). Saves 4.6 KB -> 3 blocks/CU.
    float (*off_s2)[32][18] = reinterpret_cast<float (*)[32][18]>(s_a);

    int blk = blockIdx.x;            // Bz*Hh*(Ww/32) = 2048
    int wt = blk & 3;
    int h  = (blk >> 2) & 127;
    int b  = blk >> 9;
    int w0 = wt * 32;
    int t = threadIdx.x;
    int wv = t >> 6, lane = t & 63;
    const ushort* xnb = xnh + (size_t)b * HW * 64;

    // ---- phase A: offset conv via MFMA; all 8 waves (K split in halves) ----
    {
        int wo = wv & 1, ph = (wv >> 1) & 1, kh = wv >> 2;
        int g = lane >> 4, li = lane & 15;
        int px = ph * 16 + li;
        f32x4 oacc;
        #pragma unroll
        for (int r = 0; r < 4; r++) {
            int oc = wo * 16 + g * 4 + r;
            oacc[r] = (kh == 0 && oc < 18) ? obias[oc] : 0.f;
        }
        const short8* owp = reinterpret_cast<const short8*>(owA) + (wo * 18) * 64 + lane;
        #pragma unroll
        for (int kki = 0; kki < 9; kki++) {
            int kk = kh * 9 + kki;
            int tap = kk >> 1;
            int ky = tap / 3 - 1, kx = tap - (tap / 3) * 3 - 1;
            int c0 = (kk & 1) * 32 + g * 8;
            int gy = h + ky, gx = w0 + px + kx;
            bool valid = ((unsigned)gy < 128u) && ((unsigned)gx < 128u);
            short8 bf = {0, 0, 0, 0, 0, 0, 0, 0};
            if (valid)
                bf = *reinterpret_cast<const short8*>(&xnb[(((gy << 7) + gx) << 6) + c0]);
            short8 af = owp[kk * 64];
            oacc = __builtin_amdgcn_mfma_f32_16x16x32_bf16(af, bf, oacc, 0, 0, 0);
        }
        #pragma unroll
        for (int r = 0; r < 4; r++) {
            int oc = wo * 16 + g * 4 + r;
            if (oc < 18) off_s2[kh][px][oc] = oacc[r];
        }
    }
    __syncthreads();

    // ---- phase 0: bilinear coords -> corner byte-addrs + folded weights ----
    uint aw_l[8];
    bool has_unit = (t < 288);
    if (has_unit) {
        int px = t / 9, k = t - px * 9;
        int ky = k / 3 - 1, kx = k - (k / 3) * 3 - 1;
        float ody = off_s2[0][px][2 * k]     + off_s2[1][px][2 * k];
        float odx = off_s2[0][px][2 * k + 1] + off_s2[1][px][2 * k + 1];
        float cy = (float)(h + ky) + ody;
        float cx = (float)(w0 + px + kx) + odx;
        float fy = floorf(cy), fx = floorf(cx);
        float wy = cy - fy, wx = cx - fx;
        int y0 = (int)fy, x0 = (int)fx;
        int yy[2] = {y0, y0 + 1}; int xx[2] = {x0, x0 + 1};
        float wyv[2] = {1.f - wy, wy}; float wxv[2] = {1.f - wx, wx};
        #pragma unroll
        for (int ci = 0; ci < 2; ci++)
        #pragma unroll
        for (int cj = 0; cj < 2; cj++) {
            int yv = yy[ci], xv = xx[cj];
            bool val = ((unsigned)yv < 128u) && ((unsigned)xv < 128u);
            int ycl = min(max(yv, 0), 127), xcl = min(max(xv, 0), 127);
            int slot = ci * 2 + cj;
            aw_l[slot * 2]     = (uint)(((ycl << 7) + xcl) << 7);  // byte addr
            aw_l[slot * 2 + 1] = __float_as_uint(val ? wyv[ci] * wxv[cj] : 0.f);
        }
    }
    __syncthreads();                       // off_s2 (in s_a) now dead
    if (has_unit) {
        uint base = (uint)t * 8;
        #pragma unroll
        for (int i = 0; i < 8; i++) s_aw[base + i] = aw_l[i];
    }
    __syncthreads();

    // ---- phase 1: dwordx4 gather; 8 lanes per (px,tap) unit, 8 ch/lane ----
    {
        int sub = lane >> 3;               // unit slot within iteration
        int ci  = lane & 7;                // channel group: channels ci*8..ci*8+7
        int co  = ci << 4;                 // byte offset of channel group
        const char* xnc = reinterpret_cast<const char*>(xnb);
        char* s_ab = reinterpret_cast<char*>(s_a);
        #pragma unroll
        for (int i = 0; i < 5; i++) {
            int lu = i * 8 + sub;
            if (lu < 36) {
                int U = wv * 36 + lu;      // unit = px*9 + tap
                int px = U / 9;
                int tap = U - px * 9;
                const uint4 q0 = *reinterpret_cast<const uint4*>(&s_aw[U * 8]);
                const uint4 q1 = *reinterpret_cast<const uint4*>(&s_aw[U * 8 + 4]);
                uint4 v00 = *reinterpret_cast<const uint4*>(xnc + (q0.x + co));
                uint4 v01 = *reinterpret_cast<const uint4*>(xnc + (q0.z + co));
                uint4 v10 = *reinterpret_cast<const uint4*>(xnc + (q1.x + co));
                uint4 v11 = *reinterpret_cast<const uint4*>(xnc + (q1.z + co));
                float w00 = __uint_as_float(q0.y), w01 = __uint_as_float(q0.w);
                float w10 = __uint_as_float(q1.y), w11 = __uint_as_float(q1.w);
                float a0, a1, a2, a3, a4, a5, a6, a7;
                #define LO(u) __uint_as_float((u) << 16)
                #define HI(u) __uint_as_float((u) & 0xffff0000u)
                a0 = w00 * LO(v00.x); a1 = w00 * HI(v00.x);
                a2 = w00 * LO(v00.y); a3 = w00 * HI(v00.y);
                a4 = w00 * LO(v00.z); a5 = w00 * HI(v00.z);
                a6 = w00 * LO(v00.w); a7 = w00 * HI(v00.w);
                a0 = fmaf(w01, LO(v01.x), a0); a1 = fmaf(w01, HI(v01.x), a1);
                a2 = fmaf(w01, LO(v01.y), a2); a3 = fmaf(w01, HI(v01.y), a3);
                a4 = fmaf(w01, LO(v01.z), a4); a5 = fmaf(w01, HI(v01.z), a5);
                a6 = fmaf(w01, LO(v01.w), a6); a7 = fmaf(w01, HI(v01.w), a7);
                a0 = fmaf(w10, LO(v10.x), a0); a1 = fmaf(w10, HI(v10.x), a1);
                a2 = fmaf(w10, LO(v10.y), a2); a3 = fmaf(w10, HI(v10.y), a3);
                a4 = fmaf(w10, LO(v10.z), a4); a5 = fmaf(w10, HI(v10.z), a5);
                a6 = fmaf(w10, LO(v10.w), a6); a7 = fmaf(w10, HI(v10.w), a7);
                a0 = fmaf(w11, LO(v11.x), a0); a1 = fmaf(w11, HI(v11.x), a1);
                a2 = fmaf(w11, LO(v11.y), a2); a3 = fmaf(w11, HI(v11.y), a3);
                a4 = fmaf(w11, LO(v11.z), a4); a5 = fmaf(w11, HI(v11.z), a5);
                a6 = fmaf(w11, LO(v11.w), a6); a7 = fmaf(w11, HI(v11.w), a7);
                #undef LO
                #undef HI
                float2 p01; p01.x = a0; p01.y = a1;
                float2 p23; p23.x = a2; p23.y = a3;
                float2 p45; p45.x = a4; p45.y = a5;
                float2 p67; p67.x = a6; p67.y = a7;
                __hip_bfloat162 b01 = __float22bfloat162_rn(p01);
                __hip_bfloat162 b23 = __float22bfloat162_rn(p23);
                __hip_bfloat162 b45 = __float22bfloat162_rn(p45);
                __hip_bfloat162 b67 = __float22bfloat162_rn(p67);
                uint4 outv;
                outv.x = *reinterpret_cast<uint*>(&b01);
                outv.y = *reinterpret_cast<uint*>(&b23);
                outv.z = *reinterpret_cast<uint*>(&b45);
                outv.w = *reinterpret_cast<uint*>(&b67);
                *reinterpret_cast<uint4*>(s_ab + px * 1168 + tap * 128 + co) = outv;
            }
        }
    }
    __syncthreads();

    // ---- phase 2: deform MFMA. wave = (ph, wo); D[oc][px] ----
    int wo = wv & 3, ph = wv >> 2;
    int g = lane >> 4, li = lane & 15;
    f32x4 acc;
    const float* bp = bias + wo * 16 + g * 4;
    acc.x = bp[0]; acc.y = bp[1]; acc.z = bp[2]; acc.w = bp[3];
    const short8* ap = reinterpret_cast<const short8*>(wA) + (wo * 18) * 64 + lane;
    const ushort* sp = s_a + (ph * 16 + li) * 584 + g * 8;
    #pragma unroll
    for (int kk = 0; kk < 18; kk++) {
        short8 af = ap[kk * 64];                                    // weights (arg0)
        short8 bf = *reinterpret_cast<const short8*>(sp + kk * 32); // samples (arg1)
        acc = __builtin_amdgcn_mfma_f32_16x16x32_bf16(af, bf, acc, 0, 0, 0);
    }
    size_t ybase = ((size_t)(b * 64 + wo * 16 + g * 4)) * HW + h * Ww + w0 + ph * 16 + li;
    y[ybase]           = acc.x;
    y[ybase + HW]      = acc.y;
    y[ybase + 2 * HW]  = acc.z;
    y[ybase + 3 * HW]  = acc.w;

    // ---- epilogue: GN partial sums for this block's 2048 values ----
    float s  = acc.x + acc.y + acc.z + acc.w;
    float s2 = acc.x * acc.x + acc.y * acc.y + acc.z * acc.z + acc.w * acc.w;
    #pragma unroll
    for (int o = 32; o > 0; o >>= 1) {
        s  += __shfl_down(s, o);
        s2 += __shfl_down(s2, o);
    }
    float* redbuf = reinterpret_cast<float*>(s_aw);   // s_aw is dead now
    if (lane == 0) { redbuf[wv * 2] = s; redbuf[wv * 2 + 1] = s2; }
    __syncthreads();
    if (t == 0) {
        float a = 0.f, c2 = 0.f;
        #pragma unroll
        for (int i = 0; i < 8; i++) { a += redbuf[i * 2]; c2 += redbuf[i * 2 + 1]; }
        part[blk * 2]     = a;
        part[blk * 2 + 1] = c2;
    }
}

// shared per-block reduction of one sample's 512 partial pairs -> (mean, rsqrt)
__device__ __forceinline__ void gn_reduce_stats(const float* __restrict__ part, int b,
                                                int t, float& m_out, float& rs_out) {
    __shared__ float ls[4][2];
    __shared__ float s_ms[2];
    int i0 = (b * 512 + t) * 2, i1 = (b * 512 + 256 + t) * 2;
    float s  = part[i0]     + part[i1];
    float s2 = part[i0 + 1] + part[i1 + 1];
    #pragma unroll
    for (int o = 32; o > 0; o >>= 1) {
        s  += __shfl_down(s, o);
        s2 += __shfl_down(s2, o);
    }
    int wave = t >> 6, lane = t & 63;
    if (lane == 0) { ls[wave][0] = s; ls[wave][1] = s2; }
    __syncthreads();
    if (t == 0) {
        float a = 0.f, c = 0.f;
        #pragma unroll
        for (int i = 0; i < 4; i++) { a += ls[i][0]; c += ls[i][1]; }
        const float n = (float)(Cc * HW);
        float m = a / n;
        float var = c / n - m * m;
        s_ms[0] = m;
        s_ms[1] = rsqrtf(var + EPSf);
    }
    __syncthreads();
    m_out = s_ms[0];
    rs_out = s_ms[1];
}

// ---- block-1 finalize: GN-stats + normalize+ReLU+residual -> h1 + hnh ----
__global__ __launch_bounds__(256)
void gn_fin1_kernel(const float* __restrict__ y, const float* __restrict__ res,
                    const float* __restrict__ g, const float* __restrict__ be,
                    const float* __restrict__ part, float* __restrict__ h1,
                    ushort* __restrict__ hnh) {
    __shared__ float s_t[64][65];
    int blk = blockIdx.x;                 // Bz * (HW/64) = 1024
    int p0 = (blk & 255) * 64;
    int b = blk >> 8;
    int t = threadIdx.x;
    int tp = t & 63;
    float m, rs;
    gn_reduce_stats(part, b, t, m, rs);
    #pragma unroll
    for (int i = 0; i < 16; i++) {
        int c = i * 4 + (t >> 6);
        size_t idx = ((size_t)(b * 64 + c)) * HW + p0 + tp;
        float v = (y[idx] - m) * rs * g[c] + be[c];
        v = fmaxf(v, 0.f) + res[idx];
        h1[idx] = v;
        s_t[c][tp] = v;
    }
    __syncthreads();
    #pragma unroll
    for (int i = 0; i < 16; i++) {
        int pl = i * 4 + (t >> 6);
        hnh[((size_t)b * HW + p0 + pl) * 64 + tp] = f32_to_bf16(s_t[tp][pl]);
    }
}

// ---- block-2 finalize: GN-stats + normalize + ReLU + residual -> out ----
__global__ __launch_bounds__(256)
void gn_fin2_kernel(const float* __restrict__ y, const float* __restrict__ res,
                    const float* __restrict__ g, const float* __restrict__ be,
                    const float* __restrict__ part, float* __restrict__ out) {
    int idx = (blockIdx.x * 256 + threadIdx.x) * 4;   // B*C*H*W / 4 threads
    int c = (idx >> 14) & 63;
    int b = idx >> 20;
    float m, rs;
    gn_reduce_stats(part, b, threadIdx.x, m, rs);
    float gc = g[c], bc = be[c];
    float4 yv = *reinterpret_cast<const float4*>(y + idx);
    float4 rv = *reinterpret_cast<const float4*>(res + idx);
    float4 o;
    o.x = fmaxf((yv.x - m) * rs * gc + bc, 0.f) + rv.x;
    o.y = fmaxf((yv.y - m) * rs * gc + bc, 0.f) + rv.y;
    o.z = fmaxf((yv.z - m) * rs * gc + bc, 0.f) + rv.z;
    o.w = fmaxf((yv.w - m) * rs * gc + bc, 0.f) + rv.w;
    *reinterpret_cast<float4*>(out + idx) = o;
}

extern "C" void kernel_launch(void* const* d_in, const int* in_sizes, int n_in,
                              void* d_out, int out_size, void* d_ws, size_t ws_size,
                              hipStream_t stream) {
    const float* x   = (const float*)d_in[0];
    const float* w1  = (const float*)d_in[1];
    const float* b1  = (const float*)d_in[2];
    const float* ow1 = (const float*)d_in[3];
    const float* ob1 = (const float*)d_in[4];
    const float* g1  = (const float*)d_in[5];
    const float* be1 = (const float*)d_in[6];
    const float* w2  = (const float*)d_in[7];
    const float* b2  = (const float*)d_in[8];
    const float* ow2 = (const float*)d_in[9];
    const float* ob2 = (const float*)d_in[10];
    const float* g2  = (const float*)d_in[11];
    const float* be2 = (const float*)d_in[12];
    float* out = (float*)d_out;

    float* ws    = (float*)d_ws;
    float* ybuf  = ws;                                   // 4,194,304 f
    float* h1    = ybuf + (size_t)Bz * Cc * HW;          // 4,194,304 f
    ushort* xnh  = (ushort*)(h1 + (size_t)Bz * Cc * HW); // 4,194,304 bf16
    ushort* hnh  = xnh + (size_t)Bz * HW * 64;           // 4,194,304 bf16
    ushort* wA1  = hnh + (size_t)Bz * HW * 64;           // 36,864 bf16
    ushort* wA2  = wA1 + 36864;                          // 36,864 bf16
    ushort* owA1 = wA2 + 36864;                          // 18,432 bf16
    ushort* owA2 = owA1 + 18432;                         // 18,432 bf16
    float* part  = (float*)(owA2 + 18432);               // 4096 f

    frag_kernel<<<(110592 + 255) / 256, 256, 0, stream>>>(w1, w2, ow1, ow2, wA1, wA2, owA1, owA2);
    nhwc_kernel<<<Bz * (HW / 64), 256, 0, stream>>>(x, xnh);

    // block 1: offset-conv + deform_conv + GN-partial (fused) -> fin1
    deform_fused_kernel<<<Bz * Hh * (Ww / 32), 512, 0, stream>>>(xnh, wA1, owA1, b1, ob1, ybuf, part);
    gn_fin1_kernel<<<Bz * (HW / 64), 256, 0, stream>>>(ybuf, x, g1, be1, part, h1, hnh);

    // block 2: same, residual on h1, elementwise finalize to out
    deform_fused_kernel<<<Bz * Hh * (Ww / 32), 512, 0, stream>>>(hnh, wA2, owA2, b2, ob2, ybuf, part);
    gn_fin2_kernel<<<Bz * Cc * HW / 1024, 256, 0, stream>>>(ybuf, h1, g2, be2, part, out);
}